// Round 12
// baseline (109.760 us; speedup 1.0000x reference)
//
#include <hip/hip_runtime.h>
#include <hip/hip_bf16.h>
#include <stdint.h>

#define Bn 8
#define Sn 2048
#define Hn 768
#define Rn 768
#define Mn (Bn*Sn)          // 16384

typedef __attribute__((ext_vector_type(8))) __bf16 bf16x8;
typedef __attribute__((ext_vector_type(4))) float f32x4;
typedef __attribute__((ext_vector_type(16))) float f32x16;

__device__ __forceinline__ void gload_lds16(const void* g, void* l) {
    __builtin_amdgcn_global_load_lds(
        (const __attribute__((address_space(1))) uint32_t*)g,
        (__attribute__((address_space(3))) uint32_t*)l,
        16, 0, 0);
}

__device__ __forceinline__ unsigned short f2bf_bits(float f) {
    uint32_t u = __builtin_bit_cast(uint32_t, f);
    u += 0x7fffu + ((u >> 16) & 1u);
    return (unsigned short)(u >> 16);
}

// ---------------- convert + transpose proj: projT[r][h] = bf16(proj[h][r]) ----------------
__global__ void cvt_projT(const float* __restrict__ proj, __hip_bfloat16* __restrict__ projT) {
    int t = blockIdx.x * blockDim.x + threadIdx.x;
    if (t < Hn * Rn) {
        int r = t / Hn;
        int h = t - r * Hn;
        projT[t] = __hip_bfloat16(__builtin_bit_cast(__hip_bfloat16_raw, f2bf_bits(proj[h * Rn + r])));
    }
}

// ---------------- fused projection GEMM: R6 sbuf XCD-grouped VERBATIM (~21us measured) ----------------
// R7's dbuf variant measured +4us SLOWER (R11 vs R6 ledger) — single-buffer kept.
#define BKP 32
__global__ __launch_bounds__(256, 3)
void gemm_proj_fused(const float* __restrict__ A,            // [Mn][Hn] f32
                     const __hip_bfloat16* __restrict__ Bt,  // [Rn][Hn] bf16
                     __hip_bfloat16* __restrict__ Ct,        // [Mn][Rn] bf16
                     float* __restrict__ sqv) {              // [Mn] f32, pre-zeroed
    __shared__ float Af[128 * BKP];             // 16 KB
    __shared__ __hip_bfloat16 Bs[128 * BKP];    //  8 KB
    const int tid  = threadIdx.x;
    const int lane = tid & 63;
    const int w    = tid >> 6;
    const int wr   = w >> 1, wc = w & 1;

    const int L   = blockIdx.x;        // 0..767
    const int xcd = L & 7;
    const int q   = L >> 3;            // 0..95
    const int row0 = (xcd * 16 + q / 6) * 128;
    const int col0 = (q % 6) * 128;

    f32x4 acc[4][4];
#pragma unroll
    for (int i = 0; i < 4; ++i)
#pragma unroll
        for (int j = 0; j < 4; ++j) acc[i][j] = (f32x4){0.f, 0.f, 0.f, 0.f};

    const int cl = lane >> 4;     // 0..3
    const int rA = lane & 15;

    for (int k0 = 0; k0 < Hn; k0 += BKP) {
#pragma unroll
        for (int i = 0; i < 4; ++i) {
            int cid = tid + i * 256;
            int r = cid >> 3;
            int c = cid & 7;
            int csrc = c ^ (r & 7);
            gload_lds16(A + (size_t)(row0 + r) * Hn + k0 + csrc * 4, Af + cid * 4);
        }
#pragma unroll
        for (int i = 0; i < 2; ++i) {
            int c16 = tid + i * 256;
            int r = c16 >> 2;
            int c = c16 & 3;
            int csrc = c ^ ((r >> 1) & 3);
            gload_lds16(Bt + (size_t)(col0 + r) * Hn + k0 + csrc * 8, Bs + c16 * 8);
        }
        __syncthreads();

        bf16x8 af[4], bfr[4];
#pragma unroll
        for (int f = 0; f < 4; ++f) {
            int ra = wr * 64 + f * 16 + rA;
            int rb = wc * 64 + f * 16 + rA;
            f32x4 a0 = *(const f32x4*)(Af + ra * BKP + (((2 * cl + 0) ^ (ra & 7)) * 4));
            f32x4 a1 = *(const f32x4*)(Af + ra * BKP + (((2 * cl + 1) ^ (ra & 7)) * 4));
            union { bf16x8 v; __bf16 e[8]; } u;
#pragma unroll
            for (int p = 0; p < 4; ++p) { u.e[p] = (__bf16)a0[p]; u.e[4 + p] = (__bf16)a1[p]; }
            af[f]  = u.v;
            bfr[f] = *(const bf16x8*)(Bs + rb * BKP + (cl ^ ((rb >> 1) & 3)) * 8);
        }
#pragma unroll
        for (int fm = 0; fm < 4; ++fm)
#pragma unroll
            for (int fn = 0; fn < 4; ++fn)
                acc[fm][fn] = __builtin_amdgcn_mfma_f32_16x16x32_bf16(af[fm], bfr[fn], acc[fm][fn], 0, 0, 0);
        __syncthreads();
    }

    // epilogue: store bf16 t, accumulate row sums of rounded t^2
    const int cr = (lane >> 4) * 4;
    const int cc = lane & 15;
    float rowsum[4][4];
#pragma unroll
    for (int fm = 0; fm < 4; ++fm)
#pragma unroll
        for (int j = 0; j < 4; ++j) rowsum[fm][j] = 0.f;

#pragma unroll
    for (int fm = 0; fm < 4; ++fm)
#pragma unroll
        for (int fn = 0; fn < 4; ++fn)
#pragma unroll
            for (int j = 0; j < 4; ++j) {
                int row = row0 + wr * 64 + fm * 16 + cr + j;
                int col = col0 + wc * 64 + fn * 16 + cc;
                unsigned short bits = f2bf_bits(acc[fm][fn][j]);
                Ct[(size_t)row * Rn + col] =
                    __hip_bfloat16(__builtin_bit_cast(__hip_bfloat16_raw, bits));
                float vr = __builtin_bit_cast(float, (uint32_t)bits << 16);
                rowsum[fm][j] = fmaf(vr, vr, rowsum[fm][j]);
            }

#pragma unroll
    for (int fm = 0; fm < 4; ++fm)
#pragma unroll
        for (int j = 0; j < 4; ++j) {
            float s = rowsum[fm][j];
            s += __shfl_xor(s, 1, 64);
            s += __shfl_xor(s, 2, 64);
            s += __shfl_xor(s, 4, 64);
            s += __shfl_xor(s, 8, 64);
            if (cc == 0)
                atomicAdd(&sqv[row0 + wr * 64 + fm * 16 + cr + j], s);
        }
}

// ---------------- symmetric gram: 32x32x16 MFMA, BK=64 sbuf, XOR swizzle ----------------
// Same sync structure/staging as R6 (best measured ~74us). Changes:
//  - mfma_f32_32x32x16_bf16: 16 MFMA/K-step/wave @8cy (vs 32 @5cy) — 15% faster pipe
//    (m119: 2495 vs 2176 TF), half the issue slots, same ds_read count/bytes.
//  - C/D layout col=lane&31, row=(reg&3)+8*(reg>>2)+4*(lane>>5): main stores are
//    128B line-complete per instruction; mirror is a direct f32x4 per reg-quad
//    (rows consecutive in reg&3) — NO LDS transpose scratch, half the store instrs.
// (256,4): reg budget 128 (acc 64 + ~40 live); (256,5) spilled (R5, 2.6x slower).
#define BKG 64
__global__ __launch_bounds__(256, 4)
void gram_sym(const __hip_bfloat16* __restrict__ T, const float* __restrict__ sq,
              float* __restrict__ out) {
    __shared__ __hip_bfloat16 As[128 * BKG];   // 16 KB
    __shared__ __hip_bfloat16 Bs[128 * BKG];   // 16 KB

    const int tid  = threadIdx.x;
    const int lane = tid & 63;
    const int w    = tid >> 6;
    const int wr   = w >> 1, wc = w & 1;
    const int r32  = lane & 31;
    const int hi   = lane >> 5;

    const int L = blockIdx.x;
    const int b = L & 7;
    int tile_id = L >> 3;               // 0..135
    int ty = 0;
    {
        int rowlen = 16;
        while (tile_id >= rowlen) { tile_id -= rowlen; --rowlen; ++ty; }
    }
    const int tx = ty + tile_id;
    const bool diag = (ty == tx);
    const int row0 = ty * 128;
    const int col0 = tx * 128;

    const __hip_bfloat16* Tb = T + (size_t)b * Sn * Rn;
    const float* sqb = sq + b * Sn;
    float* outb = out + (size_t)b * Sn * Sn;

    f32x16 acc[2][2];
#pragma unroll
    for (int i = 0; i < 2; ++i)
#pragma unroll
        for (int j = 0; j < 2; ++j)
#pragma unroll
            for (int e = 0; e < 16; ++e) acc[i][j][e] = 0.f;

    for (int k0 = 0; k0 < Rn; k0 += BKG) {
#pragma unroll
        for (int i = 0; i < 4; ++i) {
            int cid = tid + i * 256;
            int r = cid >> 3;
            int c = cid & 7;
            int csrc = c ^ (r & 7);
            gload_lds16(Tb + (size_t)(row0 + r) * Rn + k0 + csrc * 8, As + cid * 8);
            if (!diag)
                gload_lds16(Tb + (size_t)(col0 + r) * Rn + k0 + csrc * 8, Bs + cid * 8);
        }
        __syncthreads();

        const __hip_bfloat16* Bsrc = diag ? As : Bs;
#pragma unroll
        for (int ks = 0; ks < 4; ++ks) {        // four K=16 sub-steps of the 64-k tile
            const int ck = ks * 2 + hi;         // logical 16B chunk (8 bf16 = k 8ck..8ck+7)
            bf16x8 af[2], bfr[2];
#pragma unroll
            for (int f = 0; f < 2; ++f) {
                int ra = wr * 64 + f * 32 + r32;
                int rb = wc * 64 + f * 32 + r32;
                af[f]  = *(const bf16x8*)(As   + ra * BKG + ((ck ^ (ra & 7)) * 8));
                bfr[f] = *(const bf16x8*)(Bsrc + rb * BKG + ((ck ^ (rb & 7)) * 8));
            }
#pragma unroll
            for (int fm = 0; fm < 2; ++fm)
#pragma unroll
                for (int fn = 0; fn < 2; ++fn)
                    acc[fm][fn] = __builtin_amdgcn_mfma_f32_32x32x16_bf16(af[fm], bfr[fn], acc[fm][fn], 0, 0, 0);
        }
        __syncthreads();
    }

    // epilogue: D(row,col) with col = C0 + r32, row = R0 + (reg&3) + 8*(reg>>2) + 4*hi
#pragma unroll
    for (int fm = 0; fm < 2; ++fm)
#pragma unroll
        for (int fn = 0; fn < 2; ++fn) {
            const int R0 = row0 + wr * 64 + fm * 32;
            const int C0 = col0 + wc * 64 + fn * 32;
            const int col = C0 + r32;
            const float sqc = sqb[col];
            float v[16];
#pragma unroll
            for (int g = 0; g < 4; ++g)
#pragma unroll
                for (int r = 0; r < 4; ++r) {
                    const int reg = g * 4 + r;
                    const int row = R0 + r + 8 * g + 4 * hi;
                    v[reg] = fmaxf(sqb[row] + sqc - 2.0f * acc[fm][fn][reg], 0.0f);
                    outb[(size_t)row * Sn + col] = v[reg];   // 32 lanes -> 128B line
                }
            if (!diag) {
                // mirror: rows r+8g+4hi consecutive in r -> direct f32x4 at out[col][...]
#pragma unroll
                for (int g = 0; g < 4; ++g) {
                    f32x4 mv = {v[g * 4 + 0], v[g * 4 + 1], v[g * 4 + 2], v[g * 4 + 3]};
                    *(f32x4*)&outb[(size_t)col * Sn + R0 + 8 * g + 4 * hi] = mv;
                }
            }
        }
}

extern "C" void kernel_launch(void* const* d_in, const int* in_sizes, int n_in,
                              void* d_out, int out_size, void* d_ws, size_t ws_size,
                              hipStream_t stream) {
    const float* batch = (const float*)d_in[0];   // [8][2048][768] f32
    const float* proj  = (const float*)d_in[1];   // [768][768] f32
    float* out = (float*)d_out;                   // [8][2048][2048] f32

    char* ws = (char*)d_ws;
    __hip_bfloat16* projT = (__hip_bfloat16*)(ws);                 //  1,179,648 B
    __hip_bfloat16* t_bf  = (__hip_bfloat16*)(ws + 1179648);       // 25,165,824 B
    float*          sqv   = (float*)(ws + 1179648 + 25165824);     //     65,536 B

    (void)hipMemsetAsync(sqv, 0, Mn * sizeof(float), stream);
    cvt_projT<<<(Hn * Rn + 255) / 256, 256, 0, stream>>>(proj, projT);
    gemm_proj_fused<<<768, 256, 0, stream>>>(batch, projT, t_bf, sqv);
    gram_sym<<<8 * 136, 256, 0, stream>>>(t_bf, sqv, out);
}